// Round 5
// baseline (174.786 us; speedup 1.0000x reference)
//
#include <hip/hip_runtime.h>
#include <hip/hip_bf16.h>
#include <stdint.h>

typedef __attribute__((ext_vector_type(8))) __bf16 bf16x8;
typedef __attribute__((ext_vector_type(4))) float f32x4;

#define N_PTS 1600
#define HD    64

// ---- ws layout (bytes). Region [0, 6.55 MB) is time-multiplexed:
// prep outputs (Xc/WT/bias, dead after k_proj) + VhT (dead after k_smooth),
// then Opart (written only by k_attn). Total 9.22 MB (9.83 MB proven OK in R4).
#define OFF_XC    0u          //  819200 : [1600][256] bf16 canonical x
#define OFF_WT    819200u     //  393216 : 3 x [256 o][256 k] bf16 transposed W
#define OFF_BIAS  1212416u    //    1536 : 3 x 256 bf16
#define OFF_VHT   1213952u    //  819200 : [4][64][1600] raw V^T
#define OFF_OP    0u          // 6553600 : [2 z][4 kg][1600 n][256 o] bf16 unnormalized O partials
#define OFF_LP    6553600u    //  204800 : [2 z][4 kg][4 hq][1600 n] f32 denom partials
#define OFF_QH    6758400u    //  819200 : [4][1600][64] bf16 Q (pre-scaled 1/16)
#define OFF_KH    7577600u    //  819200 : [4][1600][64] bf16 K
#define OFF_VST   8396800u    //  819200 : [4][64][1600] bf16 smoothed V^T

__device__ __forceinline__ float bf2f(ushort h) {
  union { uint32_t u; float f; } v; v.u = ((uint32_t)h) << 16; return v.f;
}
__device__ __forceinline__ ushort f2bf(float f) {
  union { float f; uint32_t u; } v; v.f = f;
  uint32_t u = v.u;
  return (ushort)((u + 0x7FFFu + ((u >> 16) & 1u)) >> 16);
}

// block-uniform dtype detection: sample 1024 even-index ushorts from x's first 4 KB.
// f32 buffers put mantissa garbage there (huge/NaN bf16 decodes); bf16 stays ~N(0,1).
__device__ __forceinline__ int detect_f32(const ushort* xu, int* shflag) {
  int t = threadIdx.x & 255;
  if (t == 0) *shflag = 0;
  __syncthreads();
  int local = 0;
#pragma unroll
  for (int i = 0; i < 4; ++i) {
    float v = bf2f(xu[(t * 4 + i) * 2]);
    if (!(fabsf(v) < 1e4f)) local = 1;
  }
  if (local) atomicOr(shflag, 1);
  __syncthreads();
  return *shflag;
}

// ---- prep: convert x/biases to bf16, transpose+convert the 3 weight matrices ----
__global__ void k_prep(const void* __restrict__ x, const void* __restrict__ Wq,
                       const void* __restrict__ bq, const void* __restrict__ Wk,
                       const void* __restrict__ bk, const void* __restrict__ Wv,
                       const void* __restrict__ bv, char* __restrict__ ws) {
  __shared__ int shflag;
  __shared__ ushort tileb[32][33];
  int isf32 = detect_f32((const ushort*)x, &shflag);
  int b = blockIdx.x, t = threadIdx.x;

  if (b < 400) {                       // x: 409600 elems, 1024/block
    ushort4 o;
    if (isf32) {
      float4 f = ((const float4*)x)[b * 256 + t];
      o.x = f2bf(f.x); o.y = f2bf(f.y); o.z = f2bf(f.z); o.w = f2bf(f.w);
    } else {
      o = ((const ushort4*)x)[b * 256 + t];
    }
    ((ushort4*)(ws + OFF_XC))[b * 256 + t] = o;
  } else if (b < 592) {                // W transpose: 64 32x32 tiles per z
    int w = b - 400, z = w >> 6, tile = w & 63;
    const void* W = (z == 0) ? Wq : ((z == 1) ? Wk : Wv);
    int o0 = (tile & 7) * 32, k0 = (tile >> 3) * 32;
    int tx = t & 31, ty = t >> 5;
#pragma unroll
    for (int i = 0; i < 32; i += 8) {
      int kk = (k0 + ty + i) * 256 + o0 + tx;
      tileb[ty + i][tx] = isf32 ? f2bf(((const float*)W)[kk]) : ((const ushort*)W)[kk];
    }
    __syncthreads();
    ushort* WT = (ushort*)(ws + OFF_WT) + z * 65536;
#pragma unroll
    for (int i = 0; i < 32; i += 8)
      WT[(o0 + ty + i) * 256 + k0 + tx] = tileb[tx][ty + i];
  } else {                             // biases
    ushort* bb = (ushort*)(ws + OFF_BIAS);
#pragma unroll
    for (int z = 0; z < 3; ++z) {
      const void* B = (z == 0) ? bq : ((z == 1) ? bk : bv);
      bb[z * 256 + t] = isf32 ? f2bf(((const float*)B)[t]) : ((const ushort*)B)[t];
    }
  }
}

// -------- projections: 4 waves/block = 4 heads. Q pre-scaled 1/16; V written transposed --------
__launch_bounds__(256)
__global__ void k_proj(const ushort* __restrict__ X, const ushort* __restrict__ WT,
                       const ushort* __restrict__ bias3,
                       ushort* __restrict__ Qh, ushort* __restrict__ Kh, ushort* __restrict__ VhT) {
  int z = blockIdx.z;
  const ushort* WTz = WT + z * 65536;
  const ushort* bias = bias3 + z * 256;
  float scale = (z == 0) ? 0.0625f : 1.0f;
  int n0 = blockIdx.x * 16;
  int head = threadIdx.x >> 6;
  int lane = threadIdx.x & 63;
  int c = lane & 15, quad = lane >> 4;

  f32x4 acc[4];
#pragma unroll
  for (int i = 0; i < 4; ++i) acc[i] = (f32x4){0.f, 0.f, 0.f, 0.f};

  const ushort* xrow = X + (n0 + c) * 256;
#pragma unroll
  for (int kt = 0; kt < 8; ++kt) {
    bf16x8 a = *(const bf16x8*)(xrow + kt * 32 + quad * 8);
#pragma unroll
    for (int os = 0; os < 4; ++os) {
      bf16x8 bfr = *(const bf16x8*)(WTz + (head * 64 + os * 16 + c) * 256 + kt * 32 + quad * 8);
      acc[os] = __builtin_amdgcn_mfma_f32_16x16x32_bf16(a, bfr, acc[os], 0, 0, 0);
    }
  }
  if (z == 2) {
#pragma unroll
    for (int os = 0; os < 4; ++os) {
      float bval = bf2f(bias[head * 64 + os * 16 + c]);
      ushort4 v;
      v.x = f2bf(acc[os][0] + bval); v.y = f2bf(acc[os][1] + bval);
      v.z = f2bf(acc[os][2] + bval); v.w = f2bf(acc[os][3] + bval);
      *(ushort4*)(VhT + (head * 64 + os * 16 + c) * N_PTS + n0 + quad * 4) = v;
    }
  } else {
    ushort* out = (z == 0) ? Qh : Kh;
#pragma unroll
    for (int os = 0; os < 4; ++os) {
      float bval = bf2f(bias[head * 64 + os * 16 + c]);
#pragma unroll
      for (int r = 0; r < 4; ++r)
        out[head * (N_PTS * HD) + (n0 + quad * 4 + r) * HD + os * 16 + c] =
            f2bf((acc[os][r] + bval) * scale);
    }
  }
}

// --- smooth along m (coalesced): VsT[g][d][m] = sum_{sh in {-4,-2,0,2,4}} VhT[g][d][(m+sh)%1600]
__global__ void k_smooth(const ushort* __restrict__ VhT, ushort* __restrict__ VsT) {
  int idx = blockIdx.x * 256 + threadIdx.x;
  int m = idx % N_PTS;
  int base = idx - m;
  float s = 0.f;
#pragma unroll
  for (int sh = -4; sh <= 4; sh += 2)
    s += bf2f(VhT[base + ((m + sh + N_PTS) % N_PTS)]);
  VsT[idx] = f2bf(s);
}

// ---- build PV B-fragment from S^T C-layout via quad shuffles (no barrier) ----
__device__ __forceinline__ bf16x8 build_pfrag(const f32x4& s0, const f32x4& s1,
                                              int sA, int sB, bool low, float& lpart) {
  uint32_t pk[4];
#pragma unroll
  for (int r = 0; r < 4; ++r) {
    float p0 = __expf(s0[r]);
    float p1 = __expf(s1[r]);
    lpart += p0 + p1;
    __hip_bfloat162 h2 = __float22bfloat162_rn(make_float2(p0, p1));
    union { __hip_bfloat162 h; uint32_t u; } cv; cv.h = h2;
    pk[r] = cv.u;
  }
  union { ushort us[8]; bf16x8 v; } pb;
#pragma unroll
  for (int j = 0; j < 4; ++j) {
    uint32_t u = (uint32_t)__shfl((int)pk[j], sA, 64);
    pb.us[j] = low ? (ushort)u : (ushort)(u >> 16);
  }
#pragma unroll
  for (int j = 0; j < 4; ++j) {
    uint32_t u = (uint32_t)__shfl((int)pk[j], sB, 64);
    pb.us[4 + j] = low ? (ushort)u : (ushort)(u >> 16);
  }
  return pb.v;
}

// ---- attention: grid (100 qt, 8 = hp*4+kg, 2 z-half). 4 waves = 4 key-subsplits.
// Each wave serves heads {hp, hp+2} (shared K AND V frags). No normalization here:
// block writes bf16 O-partials + f32 L-partials; k_out divides. ----
__launch_bounds__(256, 6)
__global__ void k_attn(const ushort* __restrict__ Qh, const ushort* __restrict__ Kh,
                       const ushort* __restrict__ VsT, ushort* __restrict__ Opart,
                       float* __restrict__ Lpart) {
  int qt = blockIdx.x;
  int yy = blockIdx.y;           // hp*4 + kg
  int z  = blockIdx.z;           // key half
  int hp = yy >> 2, kg = yy & 3;
  int vg = (2 * hp - kg + 8) & 3;
  int tid = threadIdx.x, sp = tid >> 6, lane = tid & 63;
  int c = lane & 15, quad = lane >> 4;
  int n0 = qt * 16;

  __shared__ ushort ObufT[2][4][16][72];  // [head][sp][q][d] bf16, 144 B rows
  __shared__ float Lbuf[2][4][16];

  const ushort* q0row = Qh + ((hp    ) * N_PTS + n0 + c) * HD;
  const ushort* q1row = Qh + ((hp + 2) * N_PTS + n0 + c) * HD;
  bf16x8 qa00 = *(const bf16x8*)(q0row + quad * 8);
  bf16x8 qa01 = *(const bf16x8*)(q0row + 32 + quad * 8);
  bf16x8 qa10 = *(const bf16x8*)(q1row + quad * 8);
  bf16x8 qa11 = *(const bf16x8*)(q1row + 32 + quad * 8);

  f32x4 oacc0[4], oacc1[4];
#pragma unroll
  for (int i = 0; i < 4; ++i) {
    oacc0[i] = (f32x4){0.f, 0.f, 0.f, 0.f};
    oacc1[i] = (f32x4){0.f, 0.f, 0.f, 0.f};
  }
  float lp0 = 0.f, lp1 = 0.f;

  // 25 tiles per half, split 7/6/6/6 across the 4 waves
  int off = (sp == 0) ? 0 : (sp == 1) ? 7 : (sp == 2) ? 13 : 19;
  int iters = (sp == 0) ? 7 : 6;
  int kbase = z * 800 + off * 32;
  int sA = c + 16 * ((quad & 1) * 2);
  int sB = sA + 16;
  bool low = (quad < 2);
  const f32x4 z4 = (f32x4){0.f, 0.f, 0.f, 0.f};

  for (int it = 0; it < iters; ++it) {
    int key0 = kbase + it * 32;
    const ushort* krow = Kh + (kg * N_PTS + key0 + c) * HD;
    bf16x8 kb00 = *(const bf16x8*)(krow + quad * 8);
    bf16x8 kb01 = *(const bf16x8*)(krow + 32 + quad * 8);
    bf16x8 kb10 = *(const bf16x8*)(krow + 16 * HD + quad * 8);
    bf16x8 kb11 = *(const bf16x8*)(krow + 16 * HD + 32 + quad * 8);
    bf16x8 vb[4];
#pragma unroll
    for (int ds = 0; ds < 4; ++ds)
      vb[ds] = *(const bf16x8*)(VsT + (vg * HD + ds * 16 + c) * N_PTS + key0 + quad * 8);

    f32x4 s0 = __builtin_amdgcn_mfma_f32_16x16x32_bf16(kb00, qa00, z4, 0, 0, 0);
    s0 = __builtin_amdgcn_mfma_f32_16x16x32_bf16(kb01, qa01, s0, 0, 0, 0);
    f32x4 s1 = __builtin_amdgcn_mfma_f32_16x16x32_bf16(kb10, qa00, z4, 0, 0, 0);
    s1 = __builtin_amdgcn_mfma_f32_16x16x32_bf16(kb11, qa01, s1, 0, 0, 0);
    bf16x8 pb = build_pfrag(s0, s1, sA, sB, low, lp0);
#pragma unroll
    for (int ds = 0; ds < 4; ++ds)
      oacc0[ds] = __builtin_amdgcn_mfma_f32_16x16x32_bf16(vb[ds], pb, oacc0[ds], 0, 0, 0);

    s0 = __builtin_amdgcn_mfma_f32_16x16x32_bf16(kb00, qa10, z4, 0, 0, 0);
    s0 = __builtin_amdgcn_mfma_f32_16x16x32_bf16(kb01, qa11, s0, 0, 0, 0);
    s1 = __builtin_amdgcn_mfma_f32_16x16x32_bf16(kb10, qa10, z4, 0, 0, 0);
    s1 = __builtin_amdgcn_mfma_f32_16x16x32_bf16(kb11, qa11, s1, 0, 0, 0);
    bf16x8 pb1 = build_pfrag(s0, s1, sA, sB, low, lp1);
#pragma unroll
    for (int ds = 0; ds < 4; ++ds)
      oacc1[ds] = __builtin_amdgcn_mfma_f32_16x16x32_bf16(vb[ds], pb1, oacc1[ds], 0, 0, 0);
  }

  // L: sum the 4 quads (lanes c, c+16, c+32, c+48 hold partials for q=c)
  lp0 += __shfl_xor(lp0, 16, 64); lp0 += __shfl_xor(lp0, 32, 64);
  lp1 += __shfl_xor(lp1, 16, 64); lp1 += __shfl_xor(lp1, 32, 64);

  // stash bf16 O^T partials: oaccX[ds] reg r = O^T[d=ds*16+quad*4+r][q=c]
#pragma unroll
  for (int ds = 0; ds < 4; ++ds) {
    union { __hip_bfloat162 h; uint32_t u; } p01, p23, q01, q23;
    p01.h = __float22bfloat162_rn(make_float2(oacc0[ds][0], oacc0[ds][1]));
    p23.h = __float22bfloat162_rn(make_float2(oacc0[ds][2], oacc0[ds][3]));
    q01.h = __float22bfloat162_rn(make_float2(oacc1[ds][0], oacc1[ds][1]));
    q23.h = __float22bfloat162_rn(make_float2(oacc1[ds][2], oacc1[ds][3]));
    int d = ds * 16 + quad * 4;
    *(uint32_t*)&ObufT[0][sp][c][d]     = p01.u;
    *(uint32_t*)&ObufT[0][sp][c][d + 2] = p23.u;
    *(uint32_t*)&ObufT[1][sp][c][d]     = q01.u;
    *(uint32_t*)&ObufT[1][sp][c][d + 2] = q23.u;
  }
  if (quad == 0) { Lbuf[0][sp][c] = lp0; Lbuf[1][sp][c] = lp1; }
  __syncthreads();

  // block-reduce over sp: thread -> (h, q, 8-wide d octet)
  int h = tid >> 7, rem = tid & 127, q = rem >> 3, d0 = (rem & 7) * 8;
  float s[8] = {0.f, 0.f, 0.f, 0.f, 0.f, 0.f, 0.f, 0.f};
#pragma unroll
  for (int sp2 = 0; sp2 < 4; ++sp2) {
    union { uint4 v; ushort us[8]; } rd;
    rd.v = *(const uint4*)&ObufT[h][sp2][q][d0];
#pragma unroll
    for (int j = 0; j < 8; ++j) s[j] += bf2f(rd.us[j]);
  }
  float l = Lbuf[h][0][q] + Lbuf[h][1][q] + Lbuf[h][2][q] + Lbuf[h][3][q];

  int hq = hp + 2 * h;
  union { uint4 v; ushort us[8]; } wr;
#pragma unroll
  for (int j = 0; j < 8; ++j) wr.us[j] = f2bf(s[j]);
  *(uint4*)&Opart[(size_t)((z * 4 + kg) * N_PTS + n0 + q) * 256 + hq * 64 + d0] = wr.v;
  if ((rem & 7) == 0)
    Lpart[((z * 4 + kg) * 4 + hq) * N_PTS + n0 + q] = l;
}

// ---- final: out(n,o) = sum_kg w(kg,hq) * (sum_z O[z][kg]) / (sum_z L[z][kg][hq]) ----
__global__ void k_out(const ushort* __restrict__ Opart, const float* __restrict__ Lpart,
                      const void* __restrict__ x, void* __restrict__ out) {
  __shared__ int shflag;
  int isf32 = detect_f32((const ushort*)x, &shflag);
  int idx = blockIdx.x * 256 + threadIdx.x;
  int n = idx >> 8, o = idx & 255, hq = o >> 6;
  float acc = 0.f;
#pragma unroll
  for (int kg = 0; kg < 4; ++kg) {
    float num = bf2f(Opart[(size_t)((0 + kg) * N_PTS + n) * 256 + o]) +
                bf2f(Opart[(size_t)((4 + kg) * N_PTS + n) * 256 + o]);
    float l = Lpart[((0 + kg) * 4 + hq) * N_PTS + n] +
              Lpart[((4 + kg) * 4 + hq) * N_PTS + n];
    float w = (kg == ((hq + 2) & 3)) ? 2.f : 1.f;
    acc += w * num / l;
  }
  if (isf32) ((float*)out)[idx] = acc;
  else       ((ushort*)out)[idx] = f2bf(acc);
}

extern "C" void kernel_launch(void* const* d_in, const int* in_sizes, int n_in,
                              void* d_out, int out_size, void* d_ws, size_t ws_size,
                              hipStream_t stream) {
  char* ws = (char*)d_ws;
  ushort* Xc    = (ushort*)(ws + OFF_XC);
  ushort* WT    = (ushort*)(ws + OFF_WT);
  ushort* bias3 = (ushort*)(ws + OFF_BIAS);
  ushort* VhT   = (ushort*)(ws + OFF_VHT);
  ushort* Opart = (ushort*)(ws + OFF_OP);
  float*  Lpart = (float*)(ws + OFF_LP);
  ushort* Qh    = (ushort*)(ws + OFF_QH);
  ushort* Kh    = (ushort*)(ws + OFF_KH);
  ushort* VsT   = (ushort*)(ws + OFF_VST);

  k_prep<<<593, 256, 0, stream>>>(d_in[0], d_in[1], d_in[2], d_in[3],
                                  d_in[4], d_in[5], d_in[6], ws);
  k_proj<<<dim3(100, 1, 3), 256, 0, stream>>>(Xc, WT, bias3, Qh, Kh, VhT);
  k_smooth<<<1600, 256, 0, stream>>>(VhT, VsT);
  k_attn<<<dim3(100, 8, 2), 256, 0, stream>>>(Qh, Kh, VsT, Opart, Lpart);
  k_out<<<1600, 256, 0, stream>>>(Opart, Lpart, d_in[0], d_out);
}